// Round 5
// baseline (227.930 us; speedup 1.0000x reference)
//
#include <hip/hip_runtime.h>

// NewtonImplicitNet via Picard iteration, wave-private MFMA edition.
// R4 -> R5: R4's 4-wave block needed __syncthreads every Picard iteration;
// measured 1800 cyc/iter vs ~300 paper cost (barrier + LDS drain, nothing
// co-resident to overlap). Row-parallelism is capped at 128 tiles (M=16),
// so instead: 128 blocks x 1 wave; each wave owns 16 rows x ALL 128 units.
// W frags (8 N-tiles x 4 K-steps) register-resident: 128 VGPRs, OK at
// __launch_bounds__(64,1). Per iter: 4 ds_read_b128 + 32 MFMA + 32 tanh +
// 32 ds_write_b16, NO barrier (same-wave LDS ordering via lgkmcnt).
// NIT 20->14 (residual <~6e-4 worst case, f16 noise ~1e-3 dominates).

#define B_ROWS  2048
#define D_IN    784
#define UNITS   128
#define D_OUT   10
#define NIT     14
#define ZSTR    136     // f16 Z row stride (272 B: 16B-aligned, +4-bank rotate/row)
#define HSTR    132     // f32 head row stride

typedef _Float16 f16x8 __attribute__((ext_vector_type(8)));
typedef float    f32x4 __attribute__((ext_vector_type(4)));

__device__ __forceinline__ float rcp_fast(float x) { return __builtin_amdgcn_rcpf(x); }

__device__ __forceinline__ float tanh_fast(float x) {
  // tanh(x) = 1 - 2/(e^{2x}+1); saturates correctly for large |x|
  float e = __expf(2.0f * x);
  return 1.0f - 2.0f * rcp_fast(e + 1.0f);
}

__device__ __forceinline__ f16x8 cvt8(f32x4 a, f32x4 b) {
  f16x8 r;
  r[0] = (_Float16)a[0]; r[1] = (_Float16)a[1]; r[2] = (_Float16)a[2]; r[3] = (_Float16)a[3];
  r[4] = (_Float16)b[0]; r[5] = (_Float16)b[1]; r[6] = (_Float16)b[2]; r[7] = (_Float16)b[3];
  return r;
}
__device__ __forceinline__ f16x8 res8(f32x4 a, f32x4 b, f16x8 hi) {
  f16x8 r;
  r[0] = (_Float16)(a[0] - (float)hi[0]); r[1] = (_Float16)(a[1] - (float)hi[1]);
  r[2] = (_Float16)(a[2] - (float)hi[2]); r[3] = (_Float16)(a[3] - (float)hi[3]);
  r[4] = (_Float16)(b[0] - (float)hi[4]); r[5] = (_Float16)(b[1] - (float)hi[5]);
  r[6] = (_Float16)(b[2] - (float)hi[6]); r[7] = (_Float16)(b[3] - (float)hi[7]);
  return r;
}

#define MFMA(a, b, c) __builtin_amdgcn_mfma_f32_16x16x32_f16((a), (b), (c), 0, 0, 0)

// Fragment conventions (validated by R4 passing):
//   A: lane holds A[m=lo16][k = 32s + quad*8 + j], j=0..7
//   B: lane holds B[k = 32s + quad*8 + j][n=lo16]  (= Wrow[n][k..] row-major)
//   C/D: lane holds D[m = quad*4 + i][n=lo16], i=0..3

__global__ __launch_bounds__(64, 1) void fused_net(
    const float* __restrict__ x,
    const float* __restrict__ W_in,
    const float* __restrict__ b_in,
    const float* __restrict__ W1,
    const float* __restrict__ W2,
    const float* __restrict__ W3,
    const float* __restrict__ W4,
    const float* __restrict__ W_out,
    const float* __restrict__ b_out,
    float* __restrict__ out)
{
  __shared__ __align__(16) _Float16 Zb[16][ZSTR];  // Picard iterate (f16), single buffer
  __shared__ __align__(16) float    Zh[16][HSTR];  // final z4 (f32) for the head

  const int l    = threadIdx.x;   // 0..63
  const int lo16 = l & 15;
  const int quad = l >> 4;
  const int r0   = blockIdx.x * 16;

  // ================= input GEMM: xf = x @ W_in.T + b_in (f16 hi/lo split) =================
  f32x4 xf[8];
  {
    f32x4 acc[8];
#pragma unroll
    for (int nt = 0; nt < 8; ++nt) acc[nt] = (f32x4){0.f, 0.f, 0.f, 0.f};

    const float* xrow = x + (size_t)(r0 + lo16) * D_IN;
    const f16x8 zero8 = {};

#pragma unroll 1
    for (int s = 0; s < 25; ++s) {            // 25 chunks of 32 cover 784 (+16 pad)
      const int k  = s * 32 + quad * 8;
      const int kc = (k > 776) ? 776 : k;     // clamp keeps loads in-bounds
      const bool vld = (k + 8) <= D_IN;
      f32x4 xa = *(const f32x4*)(xrow + kc);
      f32x4 xb = *(const f32x4*)(xrow + kc + 4);
      f16x8 ahi = cvt8(xa, xb);
      f16x8 alo = res8(xa, xb, ahi);
      if (!vld) { ahi = zero8; alo = zero8; } // zero A side -> zero contribution
#pragma unroll
      for (int nt = 0; nt < 8; ++nt) {
        const float* wr = W_in + (size_t)(16 * nt + lo16) * D_IN + kc;
        f32x4 wa = *(const f32x4*)(wr);
        f32x4 wb = *(const f32x4*)(wr + 4);
        f16x8 bhi = cvt8(wa, wb);
        f16x8 blo = res8(wa, wb, bhi);
        acc[nt] = MFMA(ahi, bhi, acc[nt]);
        acc[nt] = MFMA(ahi, blo, acc[nt]);
        acc[nt] = MFMA(alo, bhi, acc[nt]);
      }
    }
#pragma unroll
    for (int nt = 0; nt < 8; ++nt) {
      float bb = b_in[16 * nt + lo16];
#pragma unroll
      for (int i = 0; i < 4; ++i) xf[nt][i] = acc[nt][i] + bb;
    }
  }

  // ================= 4 implicit blocks: z = tanh(z @ W.T + xf), Picard =================
  const float* const Ws[4] = {W1, W2, W3, W4};

#pragma unroll 1
  for (int wb = 0; wb < 4; ++wb) {
    // W frags, B-layout, register-resident: wf[nt][s] = W[16nt+lo16][32s+quad*8 ..+7]
    f16x8 wf[8][4];
#pragma unroll
    for (int nt = 0; nt < 8; ++nt) {
      const float* wr = Ws[wb] + (size_t)(16 * nt + lo16) * UNITS;
#pragma unroll
      for (int s = 0; s < 4; ++s) {
        const int k = s * 32 + quad * 8;
        wf[nt][s] = cvt8(*(const f32x4*)(wr + k), *(const f32x4*)(wr + k + 4));
      }
    }

    // z0 = tanh(xf)
#pragma unroll
    for (int nt = 0; nt < 8; ++nt)
#pragma unroll
      for (int i = 0; i < 4; ++i)
        Zb[quad * 4 + i][16 * nt + lo16] = (_Float16)tanh_fast(xf[nt][i]);

#pragma unroll 1
    for (int it = 0; it < NIT; ++it) {
      // A-frags: Z[m=lo16][32s + quad*8 ..+7] — same-wave RAW, no barrier needed
      f16x8 a0 = *(const f16x8*)&Zb[lo16][quad * 8];
      f16x8 a1 = *(const f16x8*)&Zb[lo16][32 + quad * 8];
      f16x8 a2 = *(const f16x8*)&Zb[lo16][64 + quad * 8];
      f16x8 a3 = *(const f16x8*)&Zb[lo16][96 + quad * 8];
      f32x4 c[8];
#pragma unroll
      for (int nt = 0; nt < 8; ++nt) c[nt] = xf[nt];     // C = xf: "+x" for free
#pragma unroll
      for (int nt = 0; nt < 8; ++nt) c[nt] = MFMA(a0, wf[nt][0], c[nt]);
#pragma unroll
      for (int nt = 0; nt < 8; ++nt) c[nt] = MFMA(a1, wf[nt][1], c[nt]);
#pragma unroll
      for (int nt = 0; nt < 8; ++nt) c[nt] = MFMA(a2, wf[nt][2], c[nt]);
#pragma unroll
      for (int nt = 0; nt < 8; ++nt) c[nt] = MFMA(a3, wf[nt][3], c[nt]);

      if (it == NIT - 1) {
        // block output tanh(z@W.T+xf) stays f32 in regs -> next block's xf
#pragma unroll
        for (int nt = 0; nt < 8; ++nt)
#pragma unroll
          for (int i = 0; i < 4; ++i) xf[nt][i] = tanh_fast(c[nt][i]);
      } else {
#pragma unroll
        for (int nt = 0; nt < 8; ++nt)
#pragma unroll
          for (int i = 0; i < 4; ++i)
            Zb[quad * 4 + i][16 * nt + lo16] = (_Float16)tanh_fast(c[nt][i]);
      }
    }
  }

  // ================= head: logits = z4 @ W_out.T + b_out, softmax =================
#pragma unroll
  for (int nt = 0; nt < 8; ++nt)
#pragma unroll
    for (int i = 0; i < 4; ++i)
      Zh[quad * 4 + i][16 * nt + lo16] = xf[nt][i];
  // same-wave RAW on Zh handled by lgkmcnt, no barrier

  {
    const int hr = lo16;          // row 0..15
    const int g  = quad;          // col group: handles cols {g, g+4, g+8(if g<2)}
    const int c2 = (g < 2) ? (g + 8) : 9;   // clamped index, masked later
    float lg0 = b_out[g];
    float lg1 = b_out[g + 4];
    float lg2 = b_out[c2];
    const float* w0 = W_out + (size_t)g * UNITS;
    const float* w1 = W_out + (size_t)(g + 4) * UNITS;
    const float* w2 = W_out + (size_t)c2 * UNITS;
#pragma unroll 1
    for (int k = 0; k < UNITS; k += 4) {
      f32x4 zv = *(const f32x4*)&Zh[hr][k];
      f32x4 a = *(const f32x4*)(w0 + k);
      f32x4 b = *(const f32x4*)(w1 + k);
      f32x4 cc = *(const f32x4*)(w2 + k);
#pragma unroll
      for (int i = 0; i < 4; ++i) {
        lg0 = fmaf(zv[i], a[i], lg0);
        lg1 = fmaf(zv[i], b[i], lg1);
        lg2 = fmaf(zv[i], cc[i], lg2);
      }
    }
    if (g >= 2) lg2 = -1e30f;     // mask the phantom column

    float mx = fmaxf(lg0, fmaxf(lg1, lg2));
    mx = fmaxf(mx, __shfl_xor(mx, 16, 64));
    mx = fmaxf(mx, __shfl_xor(mx, 32, 64));
    float e0 = __expf(lg0 - mx);
    float e1 = __expf(lg1 - mx);
    float e2 = (g < 2) ? __expf(lg2 - mx) : 0.f;
    float sm = e0 + e1 + e2;
    sm += __shfl_xor(sm, 16, 64);
    sm += __shfl_xor(sm, 32, 64);
    float rs = rcp_fast(sm);
    float* orow = out + (size_t)(r0 + hr) * D_OUT;
    orow[g]     = e0 * rs;
    orow[g + 4] = e1 * rs;
    if (g < 2) orow[g + 8] = e2 * rs;
  }
}

extern "C" void kernel_launch(void* const* d_in, const int* in_sizes, int n_in,
                              void* d_out, int out_size, void* d_ws, size_t ws_size,
                              hipStream_t stream) {
  const float* x     = (const float*)d_in[0];
  const float* W_in  = (const float*)d_in[1];
  const float* b_in  = (const float*)d_in[2];
  const float* W1    = (const float*)d_in[3];
  const float* W2    = (const float*)d_in[4];
  const float* W3    = (const float*)d_in[5];
  const float* W4    = (const float*)d_in[6];
  const float* W_out = (const float*)d_in[7];
  const float* b_out = (const float*)d_in[8];
  float* outp = (float*)d_out;

  dim3 grid(B_ROWS / 16);       // 128 single-wave blocks, one 16-row stripe each
  dim3 block(64);
  hipLaunchKernelGGL(fused_net, grid, block, 0, stream,
                     x, W_in, b_in, W1, W2, W3, W4, W_out, b_out, outp);
}

// Round 6
// 139.502 us; speedup vs baseline: 1.6339x; 1.6339x over previous
//
#include <hip/hip_runtime.h>

// NewtonImplicitNet via Picard iteration, MFMA, 2-stripes-per-block edition.
// R4/R5 post-mortem: both showed ~5-6x wall/issue inflation at 1 wave/SIMD
// (barrier drain + LDS turnaround + transcendental latency, nothing
// co-resident to hide it; likely DVFS compounding). Row quantum M=16 caps
// stripes at 128, so co-residency must come from multi-stripe blocks:
// 64 blocks x 8 waves = 2 independent 4-wave stripe-groups per block
// -> 2 waves/SIMD interleave across groups between barriers.
// Per wave: N-split 4 (32 units, 2 N-tiles), wf = 16 VGPRs. Per iter:
// 4 ds_read_b128 + 8 mfma_16x16x32_f16 + 8 tanh + 8 ds_write_b16 + barrier,
// double-buffered Z. Input GEMM f16 hi/lo 3-term; head shuffle-16 softmax.

#define B_ROWS  2048
#define D_IN    784
#define UNITS   128
#define D_OUT   10
#define NIT     14      // even (double-buffer parity); R5 measured 9.8e-4 absmax
#define ZSTR    136     // f16 Z row stride
#define HSTR    132     // f32 head row stride

typedef _Float16 f16x8 __attribute__((ext_vector_type(8)));
typedef float    f32x4 __attribute__((ext_vector_type(4)));

__device__ __forceinline__ float rcp_fast(float x) { return __builtin_amdgcn_rcpf(x); }

__device__ __forceinline__ float tanh_fast(float x) {
  float e = __expf(2.0f * x);
  return 1.0f - 2.0f * rcp_fast(e + 1.0f);
}

__device__ __forceinline__ f16x8 cvt8(f32x4 a, f32x4 b) {
  f16x8 r;
  r[0] = (_Float16)a[0]; r[1] = (_Float16)a[1]; r[2] = (_Float16)a[2]; r[3] = (_Float16)a[3];
  r[4] = (_Float16)b[0]; r[5] = (_Float16)b[1]; r[6] = (_Float16)b[2]; r[7] = (_Float16)b[3];
  return r;
}
__device__ __forceinline__ f16x8 res8(f32x4 a, f32x4 b, f16x8 hi) {
  f16x8 r;
  r[0] = (_Float16)(a[0] - (float)hi[0]); r[1] = (_Float16)(a[1] - (float)hi[1]);
  r[2] = (_Float16)(a[2] - (float)hi[2]); r[3] = (_Float16)(a[3] - (float)hi[3]);
  r[4] = (_Float16)(b[0] - (float)hi[4]); r[5] = (_Float16)(b[1] - (float)hi[5]);
  r[6] = (_Float16)(b[2] - (float)hi[6]); r[7] = (_Float16)(b[3] - (float)hi[7]);
  return r;
}

#define MFMA(a, b, c) __builtin_amdgcn_mfma_f32_16x16x32_f16((a), (b), (c), 0, 0, 0)

// Fragment conventions (validated by R4/R5 passing):
//   A: lane holds A[m=lo16][k = 32s + quad*8 + j], j=0..7
//   B: lane holds B[k = 32s + quad*8 + j][n=lo16]  (= Wrow[n][k..] row-major)
//   C/D: lane holds D[m = quad*4 + i][n=lo16], i=0..3

__global__ __launch_bounds__(512, 1) void fused_net(
    const float* __restrict__ x,
    const float* __restrict__ W_in,
    const float* __restrict__ b_in,
    const float* __restrict__ W1,
    const float* __restrict__ W2,
    const float* __restrict__ W3,
    const float* __restrict__ W4,
    const float* __restrict__ W_out,
    const float* __restrict__ b_out,
    float* __restrict__ out)
{
  __shared__ __align__(16) _Float16 Zb[2][2][16][ZSTR];  // [buf][group][row][unit]
  __shared__ __align__(16) float    Zh[2][16][HSTR];     // final z4 per group (head)

  const int t    = threadIdx.x;
  const int wave = t >> 6;        // 0..7
  const int g    = wave >> 2;     // stripe group 0/1
  const int v    = wave & 3;      // N-chunk: units [32v, 32v+32)
  const int l    = t & 63;
  const int lo16 = l & 15;
  const int quad = l >> 4;
  const int r0   = blockIdx.x * 32 + g * 16;
  const int u0   = v * 32;

  // ========== input GEMM: xf = x @ W_in.T + b_in (f16 hi/lo, 3-term) ==========
  f32x4 acc0 = {0.f, 0.f, 0.f, 0.f};
  f32x4 acc1 = {0.f, 0.f, 0.f, 0.f};
  const float* xrow = x    + (size_t)(r0 + lo16) * D_IN;
  const float* wr0  = W_in + (size_t)(u0 + lo16) * D_IN;
  const float* wr1  = W_in + (size_t)(u0 + 16 + lo16) * D_IN;

#pragma unroll 1
  for (int s = 0; s < 25; ++s) {             // 25 chunks of 32 cover 784 (+16 pad)
    const int k  = s * 32 + quad * 8;
    const int kc = (k > 776) ? 776 : k;      // clamp keeps loads in-bounds
    const bool vld = (k + 8) <= D_IN;
    f32x4 xa = *(const f32x4*)(xrow + kc);
    f32x4 xb = *(const f32x4*)(xrow + kc + 4);
    f16x8 ahi = cvt8(xa, xb);
    f16x8 alo = res8(xa, xb, ahi);
    if (!vld) { ahi = (f16x8){}; alo = (f16x8){}; }  // zero A -> zero contribution

    f32x4 wa = *(const f32x4*)(wr0 + kc);
    f32x4 wb = *(const f32x4*)(wr0 + kc + 4);
    f16x8 bh = cvt8(wa, wb);
    f16x8 bl = res8(wa, wb, bh);
    acc0 = MFMA(ahi, bh, acc0);
    acc0 = MFMA(ahi, bl, acc0);
    acc0 = MFMA(alo, bh, acc0);

    wa = *(const f32x4*)(wr1 + kc);
    wb = *(const f32x4*)(wr1 + kc + 4);
    bh = cvt8(wa, wb);
    bl = res8(wa, wb, bh);
    acc1 = MFMA(ahi, bh, acc1);
    acc1 = MFMA(ahi, bl, acc1);
    acc1 = MFMA(alo, bh, acc1);
  }

  f32x4 xf0, xf1;   // fixed-point input, f32, D-layout
  {
    float b0 = b_in[u0 + lo16];
    float b1 = b_in[u0 + 16 + lo16];
#pragma unroll
    for (int i = 0; i < 4; ++i) { xf0[i] = acc0[i] + b0; xf1[i] = acc1[i] + b1; }
  }

  // ========== 4 implicit blocks: z = tanh(z @ W.T + xf), Picard ==========
  const float* const Ws[4] = {W1, W2, W3, W4};

#pragma unroll 1
  for (int wb = 0; wb < 4; ++wb) {
    // W frags, B-layout, 16 VGPRs: wf[nt][s] = W[u0+16nt+lo16][32s+quad*8 ..+7]
    f16x8 wf[2][4];
#pragma unroll
    for (int nt = 0; nt < 2; ++nt) {
      const float* wr = Ws[wb] + (size_t)(u0 + 16 * nt + lo16) * UNITS;
#pragma unroll
      for (int s = 0; s < 4; ++s) {
        const int k = s * 32 + quad * 8;
        wf[nt][s] = cvt8(*(const f32x4*)(wr + k), *(const f32x4*)(wr + k + 4));
      }
    }

    // z0 = tanh(xf) into buf 0 (prev wb's final read was buf 1 -> no race)
#pragma unroll
    for (int nt = 0; nt < 2; ++nt)
#pragma unroll
      for (int i = 0; i < 4; ++i)
        Zb[0][g][quad * 4 + i][u0 + 16 * nt + lo16] =
            (_Float16)tanh_fast(nt ? xf1[i] : xf0[i]);
    __syncthreads();

    int p = 0;
#pragma unroll 1
    for (int it = 0; it < NIT - 1; ++it) {
      f16x8 a0 = *(const f16x8*)&Zb[p][g][lo16][      quad * 8];
      f16x8 a1 = *(const f16x8*)&Zb[p][g][lo16][32  + quad * 8];
      f16x8 a2 = *(const f16x8*)&Zb[p][g][lo16][64  + quad * 8];
      f16x8 a3 = *(const f16x8*)&Zb[p][g][lo16][96  + quad * 8];
      f32x4 c0 = xf0;   // C = xf: the "+x" comes free via the accumulator
      f32x4 c1 = xf1;
      c0 = MFMA(a0, wf[0][0], c0);  c1 = MFMA(a0, wf[1][0], c1);
      c0 = MFMA(a1, wf[0][1], c0);  c1 = MFMA(a1, wf[1][1], c1);
      c0 = MFMA(a2, wf[0][2], c0);  c1 = MFMA(a2, wf[1][2], c1);
      c0 = MFMA(a3, wf[0][3], c0);  c1 = MFMA(a3, wf[1][3], c1);
      const int q = p ^ 1;
#pragma unroll
      for (int i = 0; i < 4; ++i) {
        Zb[q][g][quad * 4 + i][u0 + lo16]      = (_Float16)tanh_fast(c0[i]);
        Zb[q][g][quad * 4 + i][u0 + 16 + lo16] = (_Float16)tanh_fast(c1[i]);
      }
      __syncthreads();
      p = q;
    }
    // final iteration: output tanh(z@W.T+xf) stays f32 in regs -> next xf
    {
      f16x8 a0 = *(const f16x8*)&Zb[p][g][lo16][      quad * 8];
      f16x8 a1 = *(const f16x8*)&Zb[p][g][lo16][32  + quad * 8];
      f16x8 a2 = *(const f16x8*)&Zb[p][g][lo16][64  + quad * 8];
      f16x8 a3 = *(const f16x8*)&Zb[p][g][lo16][96  + quad * 8];
      f32x4 c0 = xf0;
      f32x4 c1 = xf1;
      c0 = MFMA(a0, wf[0][0], c0);  c1 = MFMA(a0, wf[1][0], c1);
      c0 = MFMA(a1, wf[0][1], c0);  c1 = MFMA(a1, wf[1][1], c1);
      c0 = MFMA(a2, wf[0][2], c0);  c1 = MFMA(a2, wf[1][2], c1);
      c0 = MFMA(a3, wf[0][3], c0);  c1 = MFMA(a3, wf[1][3], c1);
#pragma unroll
      for (int i = 0; i < 4; ++i) { xf0[i] = tanh_fast(c0[i]); xf1[i] = tanh_fast(c1[i]); }
      // NIT even: final read buffer is 1; next wb's z0 writes buf 0 — safe.
    }
  }

  // ========== head: logits = z4 @ W_out.T + b_out, softmax ==========
#pragma unroll
  for (int i = 0; i < 4; ++i) {
    Zh[g][quad * 4 + i][u0 + lo16]      = xf0[i];
    Zh[g][quad * 4 + i][u0 + 16 + lo16] = xf1[i];
  }
  __syncthreads();

  {
    const int gg  = t >> 8;        // group
    const int tg  = t & 255;
    const int hr  = tg >> 4;       // row 0..15
    const int hc  = tg & 15;       // col 0..15 (10 active)
    const int hcc = (hc < D_OUT) ? hc : 0;
    float s = b_out[hcc];
    const float* wo = W_out + (size_t)hcc * UNITS;
#pragma unroll 1
    for (int k = 0; k < UNITS; k += 4) {
      f32x4 zv = *(const f32x4*)&Zh[gg][hr][k];
      f32x4 wv = *(const f32x4*)(wo + k);
      s = fmaf(zv[0], wv[0], s);
      s = fmaf(zv[1], wv[1], s);
      s = fmaf(zv[2], wv[2], s);
      s = fmaf(zv[3], wv[3], s);
    }
    if (hc >= D_OUT) s = -1e30f;
    float mx = s;
#pragma unroll
    for (int d = 1; d < 16; d <<= 1) mx = fmaxf(mx, __shfl_xor(mx, d, 16));
    float e = (hc < D_OUT) ? __expf(s - mx) : 0.f;
    float sm = e;
#pragma unroll
    for (int d = 1; d < 16; d <<= 1) sm += __shfl_xor(sm, d, 16);
    if (hc < D_OUT)
      out[(size_t)(blockIdx.x * 32 + gg * 16 + hr) * D_OUT + hc] = e * rcp_fast(sm);
  }
}

extern "C" void kernel_launch(void* const* d_in, const int* in_sizes, int n_in,
                              void* d_out, int out_size, void* d_ws, size_t ws_size,
                              hipStream_t stream) {
  const float* x     = (const float*)d_in[0];
  const float* W_in  = (const float*)d_in[1];
  const float* b_in  = (const float*)d_in[2];
  const float* W1    = (const float*)d_in[3];
  const float* W2    = (const float*)d_in[4];
  const float* W3    = (const float*)d_in[5];
  const float* W4    = (const float*)d_in[6];
  const float* W_out = (const float*)d_in[7];
  const float* b_out = (const float*)d_in[8];
  float* outp = (float*)d_out;

  dim3 grid(B_ROWS / 32);       // 64 blocks x 8 waves: 2 stripes/block, 2 waves/SIMD
  dim3 block(512);
  hipLaunchKernelGGL(fused_net, grid, block, 0, stream,
                     x, W_in, b_in, W1, W2, W3, W4, W_out, b_out, outp);
}

// Round 7
// 111.106 us; speedup vs baseline: 2.0515x; 1.2556x over previous
//
#include <hip/hip_runtime.h>

// NewtonImplicitNet via Picard iteration, MFMA, full-chip edition.
// R6 post-mortem: 74us with only 64 CUs busy, ~0.9 GHz DVFS, and a
// latency-serialized prologue (25 unroll-1 global-load iters) + epilogue.
// R7: (1) 8-row stripes -> 256 blocks x 4 waves = all 256 CUs (MFMA tiles
// half-empty: A rows 8-15 pinned to zero -- MFMA lanes are free at 2% util);
// (2) x + W_out staged to LDS via coalesced burst; W_in depth-1 register
// prefetch; next wb's W-frags prefetched during the Picard loop;
// (3) head fully unrolled from LDS. Math identical to R6 (NIT=14, f16
// iteration, f16 hi/lo input GEMM, f32 accumulator carried across blocks).

#define B_ROWS  2048
#define D_IN    784
#define UNITS   128
#define D_OUT   10
#define RPB     8       // rows per block -> 256 blocks
#define NIT     14      // even (double-buffer parity); R5/R6 measured 9.8e-4
#define ZSTR    136     // f16 Z row stride

typedef _Float16 f16x8 __attribute__((ext_vector_type(8)));
typedef float    f32x4 __attribute__((ext_vector_type(4)));

__device__ __forceinline__ float rcp_fast(float x) { return __builtin_amdgcn_rcpf(x); }

__device__ __forceinline__ float tanh_fast(float x) {
  float e = __expf(2.0f * x);
  return 1.0f - 2.0f * rcp_fast(e + 1.0f);
}

__device__ __forceinline__ f16x8 cvt8(f32x4 a, f32x4 b) {
  f16x8 r;
  r[0] = (_Float16)a[0]; r[1] = (_Float16)a[1]; r[2] = (_Float16)a[2]; r[3] = (_Float16)a[3];
  r[4] = (_Float16)b[0]; r[5] = (_Float16)b[1]; r[6] = (_Float16)b[2]; r[7] = (_Float16)b[3];
  return r;
}
__device__ __forceinline__ f16x8 res8(f32x4 a, f32x4 b, f16x8 hi) {
  f16x8 r;
  r[0] = (_Float16)(a[0] - (float)hi[0]); r[1] = (_Float16)(a[1] - (float)hi[1]);
  r[2] = (_Float16)(a[2] - (float)hi[2]); r[3] = (_Float16)(a[3] - (float)hi[3]);
  r[4] = (_Float16)(b[0] - (float)hi[4]); r[5] = (_Float16)(b[1] - (float)hi[5]);
  r[6] = (_Float16)(b[2] - (float)hi[6]); r[7] = (_Float16)(b[3] - (float)hi[7]);
  return r;
}

#define MFMA(a, b, c) __builtin_amdgcn_mfma_f32_16x16x32_f16((a), (b), (c), 0, 0, 0)

// Fragment conventions (validated R4-R6):
//   A: lane holds A[m=lo16][k = 32s + quad*8 + j], j=0..7
//   B: lane holds B[k = 32s + quad*8 + j][n=lo16]  (= Wrow[n][k..] row-major)
//   C/D: lane holds D[m = quad*4 + i][n=lo16], i=0..3

__global__ __launch_bounds__(256, 1) void fused_net(
    const float* __restrict__ x,
    const float* __restrict__ W_in,
    const float* __restrict__ b_in,
    const float* __restrict__ W1,
    const float* __restrict__ W2,
    const float* __restrict__ W3,
    const float* __restrict__ W4,
    const float* __restrict__ W_out,
    const float* __restrict__ b_out,
    float* __restrict__ out)
{
  __shared__ __align__(16) _Float16 Zb[2][16][ZSTR];   // rows 8-15 stay zero
  __shared__ __align__(16) float    Xs[RPB][D_IN];     // staged x rows (25 KB)
  __shared__ __align__(16) float    Wo[D_OUT * UNITS]; // staged W_out (5 KB)
  __shared__ float Bo[D_OUT];
  __shared__ __align__(16) float    Zh[RPB][UNITS];    // final z4 for head
  __shared__ float Lg[RPB][D_OUT];

  const int t    = threadIdx.x;
  const int wave = t >> 6;        // 0..3, N-chunk: units [32w, 32w+32)
  const int l    = t & 63;
  const int lo16 = l & 15;
  const int quad = l >> 4;
  const int u0   = wave * 32;
  const int r0   = blockIdx.x * RPB;

  // early independent scalar loads (latency hidden under staging)
  const float bi0 = b_in[u0 + lo16];
  const float bi1 = b_in[u0 + 16 + lo16];

  const float* const Ws[4] = {W1, W2, W3, W4};

  // ---- prefetch W-frag raw data for wb=0 (consumed after staging) ----
  f32x4 raw[16];
  {
    const float* a = Ws[0] + (size_t)(u0 + lo16) * UNITS;
    const float* b = Ws[0] + (size_t)(u0 + 16 + lo16) * UNITS;
#pragma unroll
    for (int s = 0; s < 4; ++s) {
      const int k = s * 32 + quad * 8;
      raw[s * 2]      = *(const f32x4*)(a + k);
      raw[s * 2 + 1]  = *(const f32x4*)(a + k + 4);
      raw[8 + s * 2]  = *(const f32x4*)(b + k);
      raw[8 + s * 2 + 1] = *(const f32x4*)(b + k + 4);
    }
  }

  // ---- coalesced staging bursts (all loads independent -> pipelined) ----
#pragma unroll 1
  for (int idx = t; idx < RPB * (D_IN / 4); idx += 256) {
    const int row = idx / (D_IN / 4);
    const int c4  = idx % (D_IN / 4);
    *((f32x4*)&Xs[row][0] + c4) = *((const f32x4*)(x + (size_t)(r0 + row) * D_IN) + c4);
  }
#pragma unroll 1
  for (int idx = t; idx < D_OUT * UNITS / 4; idx += 256)
    *((f32x4*)Wo + idx) = *((const f32x4*)W_out + idx);
  if (t < D_OUT) Bo[t] = b_out[t];
  // zero Zb rows 8..15 in both buffers (never written again)
#pragma unroll 1
  for (int idx = t; idx < 2 * 8 * (ZSTR / 2); idx += 256) {
    const int buf = idx / (8 * (ZSTR / 2));
    const int rem = idx % (8 * (ZSTR / 2));
    ((unsigned*)&Zb[buf][8 + rem / (ZSTR / 2)][0])[rem % (ZSTR / 2)] = 0u;
  }
  __syncthreads();

  // ---- input GEMM: xf = x @ W_in.T + b_in (f16 hi/lo 3-term), x from LDS ----
  f32x4 acc0 = {0.f, 0.f, 0.f, 0.f};
  f32x4 acc1 = {0.f, 0.f, 0.f, 0.f};
  const float* wr0 = W_in + (size_t)(u0 + lo16) * D_IN;
  const float* wr1 = W_in + (size_t)(u0 + 16 + lo16) * D_IN;
  f32x4 p0a, p0b, p1a, p1b;         // depth-1 prefetch of W_in
  {
    const int kc = quad * 8;        // s=0 always valid
    p0a = *(const f32x4*)(wr0 + kc);  p0b = *(const f32x4*)(wr0 + kc + 4);
    p1a = *(const f32x4*)(wr1 + kc);  p1b = *(const f32x4*)(wr1 + kc + 4);
  }
#pragma unroll 1
  for (int s = 0; s < 25; ++s) {
    f32x4 c0a = p0a, c0b = p0b, c1a = p1a, c1b = p1b;
    if (s < 24) {
      const int kn  = (s + 1) * 32 + quad * 8;
      const int knc = (kn > 776) ? 776 : kn;
      p0a = *(const f32x4*)(wr0 + knc);  p0b = *(const f32x4*)(wr0 + knc + 4);
      p1a = *(const f32x4*)(wr1 + knc);  p1b = *(const f32x4*)(wr1 + knc + 4);
    }
    const int k  = s * 32 + quad * 8;
    const int kc = (k > 776) ? 776 : k;
    const bool act = ((k + 8) <= D_IN) && (lo16 < RPB);   // A rows 8-15 zero
    f32x4 xa = *(const f32x4*)&Xs[lo16 & 7][kc];
    f32x4 xb = *(const f32x4*)&Xs[lo16 & 7][kc + 4];
    f16x8 ahi = cvt8(xa, xb);
    f16x8 alo = res8(xa, xb, ahi);
    if (!act) { ahi = (f16x8){}; alo = (f16x8){}; }
    f16x8 bh = cvt8(c0a, c0b);
    f16x8 bl = res8(c0a, c0b, bh);
    acc0 = MFMA(ahi, bh, acc0);
    acc0 = MFMA(ahi, bl, acc0);
    acc0 = MFMA(alo, bh, acc0);
    bh = cvt8(c1a, c1b);
    bl = res8(c1a, c1b, bh);
    acc1 = MFMA(ahi, bh, acc1);
    acc1 = MFMA(ahi, bl, acc1);
    acc1 = MFMA(alo, bh, acc1);
  }
  f32x4 xf0, xf1;   // fixed-point input, f32, D-layout
#pragma unroll
  for (int i = 0; i < 4; ++i) { xf0[i] = acc0[i] + bi0; xf1[i] = acc1[i] + bi1; }

  // ---- 4 implicit blocks: z = tanh(z @ W.T + xf), Picard ----
#pragma unroll 1
  for (int wb = 0; wb < 4; ++wb) {
    f16x8 wf[2][4];
#pragma unroll
    for (int s = 0; s < 4; ++s) {
      wf[0][s] = cvt8(raw[s * 2], raw[s * 2 + 1]);
      wf[1][s] = cvt8(raw[8 + s * 2], raw[8 + s * 2 + 1]);
    }
    if (wb < 3) {   // prefetch next W during this block's Picard loop
      const float* a = Ws[wb + 1] + (size_t)(u0 + lo16) * UNITS;
      const float* b = Ws[wb + 1] + (size_t)(u0 + 16 + lo16) * UNITS;
#pragma unroll
      for (int s = 0; s < 4; ++s) {
        const int k = s * 32 + quad * 8;
        raw[s * 2]         = *(const f32x4*)(a + k);
        raw[s * 2 + 1]     = *(const f32x4*)(a + k + 4);
        raw[8 + s * 2]     = *(const f32x4*)(b + k);
        raw[8 + s * 2 + 1] = *(const f32x4*)(b + k + 4);
      }
    }

    // z0 = tanh(xf) into buf 0 (rows 0-7 only = quads 0,1)
    if (quad < 2) {
#pragma unroll
      for (int i = 0; i < 4; ++i) {
        Zb[0][quad * 4 + i][u0 + lo16]      = (_Float16)tanh_fast(xf0[i]);
        Zb[0][quad * 4 + i][u0 + 16 + lo16] = (_Float16)tanh_fast(xf1[i]);
      }
    }
    __syncthreads();

    int p = 0;
#pragma unroll 1
    for (int it = 0; it < NIT - 1; ++it) {
      f16x8 a0 = *(const f16x8*)&Zb[p][lo16][     quad * 8];
      f16x8 a1 = *(const f16x8*)&Zb[p][lo16][32 + quad * 8];
      f16x8 a2 = *(const f16x8*)&Zb[p][lo16][64 + quad * 8];
      f16x8 a3 = *(const f16x8*)&Zb[p][lo16][96 + quad * 8];
      f32x4 c0 = xf0;   // C = xf: "+x" free via the accumulator
      f32x4 c1 = xf1;
      c0 = MFMA(a0, wf[0][0], c0);  c1 = MFMA(a0, wf[1][0], c1);
      c0 = MFMA(a1, wf[0][1], c0);  c1 = MFMA(a1, wf[1][1], c1);
      c0 = MFMA(a2, wf[0][2], c0);  c1 = MFMA(a2, wf[1][2], c1);
      c0 = MFMA(a3, wf[0][3], c0);  c1 = MFMA(a3, wf[1][3], c1);
      const int q = p ^ 1;
      if (quad < 2) {
#pragma unroll
        for (int i = 0; i < 4; ++i) {
          Zb[q][quad * 4 + i][u0 + lo16]      = (_Float16)tanh_fast(c0[i]);
          Zb[q][quad * 4 + i][u0 + 16 + lo16] = (_Float16)tanh_fast(c1[i]);
        }
      }
      __syncthreads();
      p = q;
    }
    // final iteration: output stays f32 in regs -> next block's xf
    {
      f16x8 a0 = *(const f16x8*)&Zb[p][lo16][     quad * 8];
      f16x8 a1 = *(const f16x8*)&Zb[p][lo16][32 + quad * 8];
      f16x8 a2 = *(const f16x8*)&Zb[p][lo16][64 + quad * 8];
      f16x8 a3 = *(const f16x8*)&Zb[p][lo16][96 + quad * 8];
      f32x4 c0 = xf0;
      f32x4 c1 = xf1;
      c0 = MFMA(a0, wf[0][0], c0);  c1 = MFMA(a0, wf[1][0], c1);
      c0 = MFMA(a1, wf[0][1], c0);  c1 = MFMA(a1, wf[1][1], c1);
      c0 = MFMA(a2, wf[0][2], c0);  c1 = MFMA(a2, wf[1][2], c1);
      c0 = MFMA(a3, wf[0][3], c0);  c1 = MFMA(a3, wf[1][3], c1);
#pragma unroll
      for (int i = 0; i < 4; ++i) { xf0[i] = tanh_fast(c0[i]); xf1[i] = tanh_fast(c1[i]); }
      // NIT even: final read was buf 1; next wb's z0 writes buf 0 (guarded by
      // the it=NIT-2 barrier for buf-0 readers, then the z0 barrier) -- race-free.
    }
  }

  // ---- head: logits = z4 @ W_out.T + b_out, softmax ----
  if (quad < 2) {
#pragma unroll
    for (int i = 0; i < 4; ++i) {
      Zh[quad * 4 + i][u0 + lo16]      = xf0[i];
      Zh[quad * 4 + i][u0 + 16 + lo16] = xf1[i];
    }
  }
  __syncthreads();

  if (t < RPB * D_OUT) {
    const int r = t / D_OUT, c = t % D_OUT;
    float s = Bo[c];
    const float* wo = &Wo[c * UNITS];
#pragma unroll
    for (int k = 0; k < UNITS; k += 4) {
      f32x4 zv = *(const f32x4*)&Zh[r][k];
      f32x4 wv = *(const f32x4*)&wo[k];
      s = fmaf(zv[0], wv[0], s);
      s = fmaf(zv[1], wv[1], s);
      s = fmaf(zv[2], wv[2], s);
      s = fmaf(zv[3], wv[3], s);
    }
    Lg[r][c] = s;
  }
  __syncthreads();
  if (t < RPB) {
    float m = Lg[t][0];
#pragma unroll
    for (int c = 1; c < D_OUT; ++c) m = fmaxf(m, Lg[t][c]);
    float e[D_OUT];
    float sum = 0.f;
#pragma unroll
    for (int c = 0; c < D_OUT; ++c) { e[c] = __expf(Lg[t][c] - m); sum += e[c]; }
    const float rs = rcp_fast(sum);
    float* orow = out + (size_t)(r0 + t) * D_OUT;
#pragma unroll
    for (int c = 0; c < D_OUT; ++c) orow[c] = e[c] * rs;
  }
}

extern "C" void kernel_launch(void* const* d_in, const int* in_sizes, int n_in,
                              void* d_out, int out_size, void* d_ws, size_t ws_size,
                              hipStream_t stream) {
  const float* x     = (const float*)d_in[0];
  const float* W_in  = (const float*)d_in[1];
  const float* b_in  = (const float*)d_in[2];
  const float* W1    = (const float*)d_in[3];
  const float* W2    = (const float*)d_in[4];
  const float* W3    = (const float*)d_in[5];
  const float* W4    = (const float*)d_in[6];
  const float* W_out = (const float*)d_in[7];
  const float* b_out = (const float*)d_in[8];
  float* outp = (float*)d_out;

  dim3 grid(B_ROWS / RPB);      // 256 blocks x 4 waves: one 8-row stripe per CU
  dim3 block(256);
  hipLaunchKernelGGL(fused_net, grid, block, 0, stream,
                     x, W_in, b_in, W1, W2, W3, W4, W_out, b_out, outp);
}